// Round 4
// baseline (26.550 us; speedup 1.0000x reference)
//
#include <hip/hip_runtime.h>

// AGCBlock collapses: log_softmax over singleton axis == 0 -> context == 0 ->
// t == b1 (constant) -> term = relu(LN(b1))*w2^T + b2 is ONE constant C-vector.
// fold(unfold(x))/counts == x, so out[0,c,h,w] = x[0,c,h,w] + term[c].
// Pure streaming add: 64 MiB read + 64 MiB write.

#define IMGHW (512 * 512)   // 262144
#define CCH   64
#define PCH   32
#define LN_EPS 1e-5f

typedef float v4f __attribute__((ext_vector_type(4)));

// total float4 = CCH*IMGHW/4 = 4,194,304
// 2048 blocks x 256 threads x 8 float4 each (128 B/thread, deep MLP).
// Block tile = 2048 consecutive float4 -> always inside ONE channel
// (65536 float4 per channel), so term is block-uniform (scalar).
#define TOTAL4    (CCH * IMGHW / 4)
#define PER_THR   8
#define PER_BLK   (256 * PER_THR)          // 2048
#define NBLOCKS   (TOTAL4 / PER_BLK)       // 2048

__global__ __launch_bounds__(256) void agc_fused_kernel(
    const float* __restrict__ x,
    const float* __restrict__ b1,
    const float* __restrict__ gamma,
    const float* __restrict__ beta,
    const float* __restrict__ w2,   // [C, P] row-major
    const float* __restrict__ b2,
    float* __restrict__ out)
{
    const int tid = threadIdx.x;

    // Channel for this whole block (2048 float4 tile never crosses a
    // channel boundary): c = (blockIdx.x*2048) >> 16 = blockIdx.x >> 5.
    const int c = blockIdx.x >> 5;

    // Every thread computes the scalar term for its block's channel
    // directly (tiny L2-resident params; pure scalar/uniform math).
    float mu = 0.f;
    #pragma unroll
    for (int p = 0; p < PCH; ++p) mu += b1[p];
    mu *= (1.0f / PCH);
    float var = 0.f;
    #pragma unroll
    for (int p = 0; p < PCH; ++p) { float d = b1[p] - mu; var += d * d; }
    var *= (1.0f / PCH);
    const float inv = rsqrtf(var + LN_EPS);
    float tv = b2[c];
    #pragma unroll
    for (int p = 0; p < PCH; ++p) {
        float t = (b1[p] - mu) * inv * gamma[p] + beta[p];
        t = fmaxf(t, 0.f);
        tv = fmaf(t, w2[c * PCH + p], tv);
    }

    const v4f* __restrict__ x4 = (const v4f*)x;
    v4f* __restrict__ o4 = (v4f*)out;

    const int base = blockIdx.x * PER_BLK + tid;

    // Issue all 8 independent non-temporal loads, then 8 non-temporal stores.
    v4f v[PER_THR];
    #pragma unroll
    for (int k = 0; k < PER_THR; ++k)
        v[k] = __builtin_nontemporal_load(&x4[base + k * 256]);
    #pragma unroll
    for (int k = 0; k < PER_THR; ++k) {
        v4f r = v[k] + tv;
        __builtin_nontemporal_store(r, &o4[base + k * 256]);
    }
}

extern "C" void kernel_launch(void* const* d_in, const int* in_sizes, int n_in,
                              void* d_out, int out_size, void* d_ws, size_t ws_size,
                              hipStream_t stream) {
    // setup_inputs order: 0:x 1:w_mask 2:b_mask 3:w1 4:b1 5:gamma 6:beta 7:w2 8:b2
    const float* x     = (const float*)d_in[0];
    const float* b1    = (const float*)d_in[4];
    const float* gamma = (const float*)d_in[5];
    const float* beta  = (const float*)d_in[6];
    const float* w2    = (const float*)d_in[7];
    const float* b2    = (const float*)d_in[8];
    float* out = (float*)d_out;

    agc_fused_kernel<<<NBLOCKS, 256, 0, stream>>>(x, b1, gamma, beta, w2, b2, out);
}

// Round 5
// 25.231 us; speedup vs baseline: 1.0523x; 1.0523x over previous
//
#include <hip/hip_runtime.h>

// AGCBlock collapses: log_softmax over singleton axis == 0 -> context == 0 ->
// t == b1 (constant) -> term = relu(LN(b1))*w2^T + b2 is ONE constant C-vector.
// fold(unfold(x))/counts == x, so out[0,c,h,w] = x[0,c,h,w] + term[c].
// Pure streaming add: 64 MiB read + 64 MiB write (134 MB mandatory traffic).

#define IMGHW (512 * 512)   // 262144
#define CCH   64
#define PCH   32
#define LN_EPS 1e-5f

typedef float v4f __attribute__((ext_vector_type(4)));

// 4096 blocks x 256 threads x 4 float4/thread (64 B/thread).
// Block tile = 1024 consecutive float4 -> always inside ONE channel
// (65536 float4 per channel; 64 blocks per channel) -> term is block-uniform.
#define TOTAL4    (CCH * IMGHW / 4)
#define PER_THR   4
#define PER_BLK   (256 * PER_THR)          // 1024
#define NBLOCKS   (TOTAL4 / PER_BLK)       // 4096

__global__ __launch_bounds__(256) void agc_fused_kernel(
    const float* __restrict__ x,
    const float* __restrict__ b1,
    const float* __restrict__ gamma,
    const float* __restrict__ beta,
    const float* __restrict__ w2,   // [C, P] row-major
    const float* __restrict__ b2,
    float* __restrict__ out)
{
    const int tid  = threadIdx.x;
    const int base = blockIdx.x * PER_BLK + tid;

    const v4f* __restrict__ x4 = (const v4f*)x;
    v4f* __restrict__ o4 = (v4f*)out;

    // ---- Issue the bulk-stream loads FIRST (no dependency on term) ----
    v4f v0 = x4[base];
    v4f v1 = x4[base + 256];
    v4f v2 = x4[base + 512];
    v4f v3 = x4[base + 768];

    // ---- Compute block-uniform term while loads are in flight ----
    const int c = blockIdx.x >> 6;   // 64 blocks per channel
    float mu = 0.f;
    #pragma unroll
    for (int p = 0; p < PCH; ++p) mu += b1[p];
    mu *= (1.0f / PCH);
    float var = 0.f;
    #pragma unroll
    for (int p = 0; p < PCH; ++p) { float d = b1[p] - mu; var += d * d; }
    var *= (1.0f / PCH);
    const float inv = rsqrtf(var + LN_EPS);
    float tv = b2[c];
    #pragma unroll
    for (int p = 0; p < PCH; ++p) {
        float t = (b1[p] - mu) * inv * gamma[p] + beta[p];
        t = fmaxf(t, 0.f);
        tv = fmaf(t, w2[c * PCH + p], tv);
    }

    // ---- Add + non-temporal store (out is never re-read) ----
    v0 += tv; v1 += tv; v2 += tv; v3 += tv;
    __builtin_nontemporal_store(v0, &o4[base]);
    __builtin_nontemporal_store(v1, &o4[base + 256]);
    __builtin_nontemporal_store(v2, &o4[base + 512]);
    __builtin_nontemporal_store(v3, &o4[base + 768]);
}

extern "C" void kernel_launch(void* const* d_in, const int* in_sizes, int n_in,
                              void* d_out, int out_size, void* d_ws, size_t ws_size,
                              hipStream_t stream) {
    // setup_inputs order: 0:x 1:w_mask 2:b_mask 3:w1 4:b1 5:gamma 6:beta 7:w2 8:b2
    const float* x     = (const float*)d_in[0];
    const float* b1    = (const float*)d_in[4];
    const float* gamma = (const float*)d_in[5];
    const float* beta  = (const float*)d_in[6];
    const float* w2    = (const float*)d_in[7];
    const float* b2    = (const float*)d_in[8];
    float* out = (float*)d_out;

    agc_fused_kernel<<<NBLOCKS, 256, 0, stream>>>(x, b1, gamma, beta, w2, b2, out);
}